// Round 22
// baseline (2773.174 us; speedup 1.0000x reference)
//
#include <hip/hip_runtime.h>
#include <stdint.h>

#define NPTS (1u << 21)   // 4*512*1024
#define KC 256
#define KM_ITERS 10
#define CHUNK 4096
#define NCHUNK (NPTS / CHUNK)   // 512
#define FTILE 1024u             // fold tile (elements)

// -------- threefry2x32 (JAX PRNG) with explicit key, both output words ------
__device__ __forceinline__ uint32_t rotl32(uint32_t v, uint32_t s) {
  return (v << s) | (v >> (32u - s));
}

__device__ void threefry2x32_key(uint32_t k0, uint32_t k1,
                                 uint32_t c0, uint32_t c1,
                                 uint32_t* o0, uint32_t* o1) {
  uint32_t ks[3] = {k0, k1, k0 ^ k1 ^ 0x1BD11BDAu};
  uint32_t x0 = c0 + ks[0];
  uint32_t x1 = c1 + ks[1];
  const uint32_t rotA[4] = {13u, 15u, 26u, 6u};
  const uint32_t rotB[4] = {17u, 29u, 16u, 24u};
  #pragma unroll
  for (int i = 0; i < 5; ++i) {
    const uint32_t* rot = ((i & 1) == 0) ? rotA : rotB;
    #pragma unroll
    for (int r = 0; r < 4; ++r) {
      x0 += x1;
      x1 = rotl32(x1, rot[r]);
      x1 ^= x0;
    }
    x0 += ks[(i + 1) % 3];
    x1 += ks[(i + 2) % 3] + (uint32_t)(i + 1);
  }
  *o0 = x0;
  *o1 = x1;
}

// init: centers0 = x[randint(key(42),(256,),0,N)]  [R14/R16-validated: exact]
__global__ void km_init(const float* __restrict__ x, float* __restrict__ centers) {
  int j = threadIdx.x;  // 256 threads, 1 block
  uint32_t s0, s1;
  threefry2x32_key(0u, 42u, 0u, 1u, &s0, &s1);      // k2 = split(key(42))[1]
  uint32_t b0, b1;
  threefry2x32_key(s0, s1, 0u, (uint32_t)j, &b0, &b1);
  uint32_t idx = (b0 ^ b1) & (NPTS - 1u);
  centers[j] = x[idx];
}

// assign + per-chunk histogram (counts only; labels recomputed in scatter).
__global__ __launch_bounds__(256) void km_assign_hist(
    const float* __restrict__ x, const float* __restrict__ centers,
    uint32_t* __restrict__ hist) {
  __shared__ float sC[KC];
  __shared__ uint32_t sH[KC];
  const int t = threadIdx.x, b = blockIdx.x;
  sC[t] = centers[t];
  sH[t] = 0u;
  __syncthreads();

  #pragma unroll
  for (int q = 0; q < 4; ++q) {
    const int i4 = b * (CHUNK / 4) + q * 256 + t;  // float4 index
    float4 xv = reinterpret_cast<const float4*>(x)[i4];
    float d0 = 3.4e38f, d1 = 3.4e38f, d2 = 3.4e38f, d3 = 3.4e38f;
    int l0 = 0, l1 = 0, l2 = 0, l3 = 0;
    #pragma unroll 4
    for (int j = 0; j < KC; j += 4) {
      float4 cv = *reinterpret_cast<const float4*>(&sC[j]);
      float e;
      e = fabsf(xv.x - cv.x); if (e < d0) { d0 = e; l0 = j; }
      e = fabsf(xv.y - cv.x); if (e < d1) { d1 = e; l1 = j; }
      e = fabsf(xv.z - cv.x); if (e < d2) { d2 = e; l2 = j; }
      e = fabsf(xv.w - cv.x); if (e < d3) { d3 = e; l3 = j; }
      e = fabsf(xv.x - cv.y); if (e < d0) { d0 = e; l0 = j + 1; }
      e = fabsf(xv.y - cv.y); if (e < d1) { d1 = e; l1 = j + 1; }
      e = fabsf(xv.z - cv.y); if (e < d2) { d2 = e; l2 = j + 1; }
      e = fabsf(xv.w - cv.y); if (e < d3) { d3 = e; l3 = j + 1; }
      e = fabsf(xv.x - cv.z); if (e < d0) { d0 = e; l0 = j + 2; }
      e = fabsf(xv.y - cv.z); if (e < d1) { d1 = e; l1 = j + 2; }
      e = fabsf(xv.z - cv.z); if (e < d2) { d2 = e; l2 = j + 2; }
      e = fabsf(xv.w - cv.z); if (e < d3) { d3 = e; l3 = j + 2; }
      e = fabsf(xv.x - cv.w); if (e < d0) { d0 = e; l0 = j + 3; }
      e = fabsf(xv.y - cv.w); if (e < d1) { d1 = e; l1 = j + 3; }
      e = fabsf(xv.z - cv.w); if (e < d2) { d2 = e; l2 = j + 3; }
      e = fabsf(xv.w - cv.w); if (e < d3) { d3 = e; l3 = j + 3; }
    }
    atomicAdd(&sH[l0], 1u);
    atomicAdd(&sH[l1], 1u);
    atomicAdd(&sH[l2], 1u);
    atomicAdd(&sH[l3], 1u);
  }
  __syncthreads();
  hist[b * KC + t] = sH[t];
}

// parallel per-cluster exclusive scan over chunks (Hillis-Steele, exact ints).
__global__ __launch_bounds__(512) void km_scan_chunks(
    uint32_t* __restrict__ hist, uint32_t* __restrict__ clusterStart) {
  __shared__ uint32_t s[NCHUNK];
  const int k = blockIdx.x, t = threadIdx.x;
  uint32_t v = hist[t * KC + k];
  s[t] = v;
  __syncthreads();
  #pragma unroll
  for (int d = 1; d < NCHUNK; d <<= 1) {
    uint32_t u = (t >= d) ? s[t - d] : 0u;
    __syncthreads();
    s[t] += u;
    __syncthreads();
  }
  hist[t * KC + k] = s[t] - v;            // exclusive within cluster
  if (t == NCHUNK - 1) clusterStart[k] = s[t];  // total (temp)
}

// serial exclusive scan over the 256 cluster totals -> clusterStart[0..256]
__global__ void km_scan_clusters(uint32_t* __restrict__ clusterStart) {
  if (threadIdx.x != 0) return;
  uint32_t acc = 0;
  for (int j = 0; j < KC; ++j) {
    uint32_t t = clusterStart[j];
    clusterStart[j] = acc;
    acc += t;
  }
  clusterStart[KC] = acc;  // == NPTS
}

// stable scatter into sorted_x (= d_out used as scratch); recomputes labels.
__global__ __launch_bounds__(256) void km_scatter(
    const float* __restrict__ x, const float* __restrict__ centers,
    const uint32_t* __restrict__ hist, const uint32_t* __restrict__ clusterStart,
    float* __restrict__ sorted_x) {
  __shared__ float sC[KC];
  __shared__ uint32_t run[KC];
  __shared__ uint32_t cntw[4][KC];
  __shared__ uint32_t basew[4][KC];
  const int t = threadIdx.x, b = blockIdx.x;
  const int w = t >> 6, lane = t & 63;
  sC[t] = centers[t];
  run[t] = hist[b * KC + t] + clusterStart[t];
  __syncthreads();

  for (int r = 0; r < CHUNK / 256; ++r) {      // 16 rounds of 256 elements
    const int i = b * CHUNK + r * 256 + t;
    const float xv = x[i];
    float dmin = 3.4e38f;
    int lab = 0;
    #pragma unroll 4
    for (int j = 0; j < KC; j += 4) {
      float4 cv = *reinterpret_cast<const float4*>(&sC[j]);
      float e;
      e = fabsf(xv - cv.x); if (e < dmin) { dmin = e; lab = j; }
      e = fabsf(xv - cv.y); if (e < dmin) { dmin = e; lab = j + 1; }
      e = fabsf(xv - cv.z); if (e < dmin) { dmin = e; lab = j + 2; }
      e = fabsf(xv - cv.w); if (e < dmin) { dmin = e; lab = j + 3; }
    }
    unsigned long long m = ~0ULL;
    #pragma unroll
    for (int bit = 0; bit < 8; ++bit) {
      unsigned long long vote = __ballot((lab >> bit) & 1);
      m &= ((lab >> bit) & 1) ? vote : ~vote;
    }
    uint32_t rank = (uint32_t)__popcll(m & ((1ULL << lane) - 1ULL));
    uint32_t wcnt = (uint32_t)__popcll(m);
    cntw[0][t] = 0u; cntw[1][t] = 0u; cntw[2][t] = 0u; cntw[3][t] = 0u;
    __syncthreads();
    if (rank == 0) cntw[w][lab] = wcnt;
    __syncthreads();
    {
      uint32_t c0 = cntw[0][t], c1 = cntw[1][t], c2 = cntw[2][t], c3 = cntw[3][t];
      uint32_t base = run[t];
      basew[0][t] = base;
      basew[1][t] = base + c0;
      basew[2][t] = base + c0 + c1;
      basew[3][t] = base + c0 + c1 + c2;
      run[t] = base + c0 + c1 + c2 + c3;
    }
    __syncthreads();
    sorted_x[basew[w][lab] + rank] = xv;
  }
}

// ---- fold helpers: explicit register names, no token pasting ---------------
#define LOADG(p0, p1, p2, p3, p4, p5, p6, p7, base) \
  p0 = b4[(base) + 0]; p1 = b4[(base) + 1];         \
  p2 = b4[(base) + 2]; p3 = b4[(base) + 3];         \
  p4 = b4[(base) + 4]; p5 = b4[(base) + 5];         \
  p6 = b4[(base) + 6]; p7 = b4[(base) + 7];

#define FOLD4(q) s += (q).x; s += (q).y; s += (q).z; s += (q).w;

#define FOLDG(p0, p1, p2, p3, p4, p5, p6, p7) \
  FOLD4(p0) FOLD4(p1) FOLD4(p2) FOLD4(p3)     \
  FOLD4(p4) FOLD4(p5) FOLD4(p6) FOLD4(p7)

// R20-validated pipelined 256-elem ordered fold from LDS (b128 reads,
// LOAD(g+1)/FOLD(g) alternation). Returns updated running sum.
__device__ __forceinline__ float fold256_pipelined(float s, const float4* b4) {
  float4 a0, a1, a2, a3, a4, a5, a6, a7;
  float4 c0, c1, c2, c3, c4, c5, c6, c7;
  LOADG(a0, a1, a2, a3, a4, a5, a6, a7, 0)
  LOADG(c0, c1, c2, c3, c4, c5, c6, c7, 8)
  FOLDG(a0, a1, a2, a3, a4, a5, a6, a7)
  LOADG(a0, a1, a2, a3, a4, a5, a6, a7, 16)
  FOLDG(c0, c1, c2, c3, c4, c5, c6, c7)
  LOADG(c0, c1, c2, c3, c4, c5, c6, c7, 24)
  FOLDG(a0, a1, a2, a3, a4, a5, a6, a7)
  LOADG(a0, a1, a2, a3, a4, a5, a6, a7, 32)
  FOLDG(c0, c1, c2, c3, c4, c5, c6, c7)
  LOADG(c0, c1, c2, c3, c4, c5, c6, c7, 40)
  FOLDG(a0, a1, a2, a3, a4, a5, a6, a7)
  LOADG(a0, a1, a2, a3, a4, a5, a6, a7, 48)
  FOLDG(c0, c1, c2, c3, c4, c5, c6, c7)
  LOADG(c0, c1, c2, c3, c4, c5, c6, c7, 56)
  FOLDG(a0, a1, a2, a3, a4, a5, a6, a7)
  FOLDG(c0, c1, c2, c3, c4, c5, c6, c7)
  return s;
}

// guarded coalesced float4 load (zero-padded; pad is never folded)
__device__ __forceinline__ float4 guarded_ld4(const float* p, uint32_t i0,
                                              uint32_t cnt) {
  float4 v = make_float4(0.f, 0.f, 0.f, 0.f);
  if (i0 + 3u < cnt) {
    v = *reinterpret_cast<const float4*>(p + i0);
  } else {
    if (i0 + 0u < cnt) v.x = p[i0 + 0u];
    if (i0 + 1u < cnt) v.y = p[i0 + 1u];
    if (i0 + 2u < cnt) v.z = p[i0 + 2u];
  }
  return v;
}

// per-cluster sequential f32 left-fold in index order (bitwise == CPU
// scatter-add). R22 (= R21 resubmit; infra failure): tile 256 -> 1024
// (4x fewer barriers/prefetch drains; probe for overhead-bound vs
// chain-bound — R20 measured 161 us vs ~50 us model). Register prefetch =
// 4 named float4/lane. Fold ORDER bitwise unchanged: subtiles ascending
// via fold256_pipelined, scalar tail ascending.
__global__ __launch_bounds__(64) void km_fold_update(
    const float* __restrict__ sorted_x, const uint32_t* __restrict__ clusterStart,
    float* __restrict__ centers) {
  __shared__ __align__(16) float buf[2][FTILE];
  const int k = blockIdx.x;
  const uint32_t lane = threadIdx.x;
  const uint32_t s0 = clusterStart[k], s1 = clusterStart[k + 1];
  const uint32_t cnt = s1 - s0;
  const float* p = sorted_x + s0;
  const uint32_t ntiles = (cnt + FTILE - 1u) / FTILE;

  // preload tile 0 into buf[0]
  if (ntiles > 0) {
    #pragma unroll
    for (uint32_t j = 0; j < 4; ++j) {
      uint32_t o = j * 256u + lane * 4u;
      float4 v = guarded_ld4(p, o, cnt);
      *reinterpret_cast<float4*>(&buf[0][o]) = v;
    }
  }
  __syncthreads();

  float s = 0.0f;
  for (uint32_t t = 0; t < ntiles; ++t) {
    // all lanes: issue register prefetch of tile t+1 (in flight during fold)
    const bool have_next = (t + 1u < ntiles);
    float4 n0 = make_float4(0.f, 0.f, 0.f, 0.f), n1 = n0, n2 = n0, n3 = n0;
    if (have_next) {
      uint32_t base = (t + 1u) * FTILE + lane * 4u;
      n0 = guarded_ld4(p, base + 0u * 256u, cnt);
      n1 = guarded_ld4(p, base + 1u * 256u, cnt);
      n2 = guarded_ld4(p, base + 2u * 256u, cnt);
      n3 = guarded_ld4(p, base + 3u * 256u, cnt);
    }
    // lane 0: fold tile t from LDS in strict index order
    if (lane == 0) {
      const float* bb = buf[t & 1u];
      uint32_t m = cnt - t * FTILE;
      if (m > FTILE) m = FTILE;
      uint32_t off = 0;
      for (; off + 256u <= m; off += 256u)
        s = fold256_pipelined(s, reinterpret_cast<const float4*>(bb + off));
      // ragged remainder (<256), 16-batch ILP then scalar — order preserved
      uint32_t j = off;
      for (; j + 16u <= m; j += 16u) {
        float v0 = bb[j + 0], v1 = bb[j + 1], v2 = bb[j + 2], v3 = bb[j + 3];
        float v4 = bb[j + 4], v5 = bb[j + 5], v6 = bb[j + 6], v7 = bb[j + 7];
        float v8 = bb[j + 8], v9 = bb[j + 9], va = bb[j + 10], vb = bb[j + 11];
        float vc = bb[j + 12], vd = bb[j + 13], ve = bb[j + 14], vf = bb[j + 15];
        s += v0; s += v1; s += v2; s += v3;
        s += v4; s += v5; s += v6; s += v7;
        s += v8; s += v9; s += va; s += vb;
        s += vc; s += vd; s += ve; s += vf;
      }
      for (; j < m; ++j) s += bb[j];
    }
    // all lanes: land the prefetched tile into the other buffer
    if (have_next) {
      uint32_t bsel = (t + 1u) & 1u;
      uint32_t o = lane * 4u;
      *reinterpret_cast<float4*>(&buf[bsel][o + 0u * 256u]) = n0;
      *reinterpret_cast<float4*>(&buf[bsel][o + 1u * 256u]) = n1;
      *reinterpret_cast<float4*>(&buf[bsel][o + 2u * 256u]) = n2;
      *reinterpret_cast<float4*>(&buf[bsel][o + 3u * 256u]) = n3;
    }
    __syncthreads();   // single wave: cheap; publishes tile t+1
  }
  if (lane == 0 && cnt > 0) centers[k] = s / (float)cnt;  // else keep old
}

// final assign + gather: out = centers[labels] (fully overwrites d_out)
__global__ __launch_bounds__(256) void km_final(
    const float* __restrict__ x, const float* __restrict__ centers,
    float* __restrict__ out) {
  __shared__ float sC[KC];
  const int t = threadIdx.x;
  sC[t] = centers[t];
  __syncthreads();

  const int nv = (int)(NPTS / 4u);
  for (int i = blockIdx.x * blockDim.x + t; i < nv; i += gridDim.x * blockDim.x) {
    float4 xv = reinterpret_cast<const float4*>(x)[i];
    float d0 = 3.4e38f, d1 = 3.4e38f, d2 = 3.4e38f, d3 = 3.4e38f;
    int l0 = 0, l1 = 0, l2 = 0, l3 = 0;
    #pragma unroll 4
    for (int j = 0; j < KC; j += 4) {
      float4 cv = *reinterpret_cast<const float4*>(&sC[j]);
      float e;
      e = fabsf(xv.x - cv.x); if (e < d0) { d0 = e; l0 = j; }
      e = fabsf(xv.y - cv.x); if (e < d1) { d1 = e; l1 = j; }
      e = fabsf(xv.z - cv.x); if (e < d2) { d2 = e; l2 = j; }
      e = fabsf(xv.w - cv.x); if (e < d3) { d3 = e; l3 = j; }
      e = fabsf(xv.x - cv.y); if (e < d0) { d0 = e; l0 = j + 1; }
      e = fabsf(xv.y - cv.y); if (e < d1) { d1 = e; l1 = j + 1; }
      e = fabsf(xv.z - cv.y); if (e < d2) { d2 = e; l2 = j + 1; }
      e = fabsf(xv.w - cv.y); if (e < d3) { d3 = e; l3 = j + 1; }
      e = fabsf(xv.x - cv.z); if (e < d0) { d0 = e; l0 = j + 2; }
      e = fabsf(xv.y - cv.z); if (e < d1) { d1 = e; l1 = j + 2; }
      e = fabsf(xv.z - cv.z); if (e < d2) { d2 = e; l2 = j + 2; }
      e = fabsf(xv.w - cv.z); if (e < d3) { d3 = e; l3 = j + 2; }
      e = fabsf(xv.x - cv.w); if (e < d0) { d0 = e; l0 = j + 3; }
      e = fabsf(xv.y - cv.w); if (e < d1) { d1 = e; l1 = j + 3; }
      e = fabsf(xv.z - cv.w); if (e < d2) { d2 = e; l2 = j + 3; }
      e = fabsf(xv.w - cv.w); if (e < d3) { d3 = e; l3 = j + 3; }
    }
    float4 o;
    o.x = sC[l0]; o.y = sC[l1]; o.z = sC[l2]; o.w = sC[l3];
    reinterpret_cast<float4*>(out)[i] = o;
  }
}

extern "C" void kernel_launch(void* const* d_in, const int* in_sizes, int n_in,
                              void* d_out, int out_size, void* d_ws, size_t ws_size,
                              hipStream_t stream) {
  const float* x = (const float*)d_in[0];
  float* out = (float*)d_out;

  // ws layout (~516 KB; validated safe in R16-R20):
  //   [0,1K)     centers f32[256]
  //   [1K,~2K)   clusterStart u32[257]
  //   [4K,516K)  hist u32[512][256]
  // sorted_x (8 MB) lives in d_out — dead after fold, overwritten by km_final.
  uint8_t* ws = (uint8_t*)d_ws;
  float* centers = (float*)(ws + 0);
  uint32_t* clusterStart = (uint32_t*)(ws + 1024);
  uint32_t* hist = (uint32_t*)(ws + 4096);
  float* sorted_x = (float*)d_out;

  km_init<<<1, KC, 0, stream>>>(x, centers);
  for (int it = 0; it < KM_ITERS; ++it) {
    km_assign_hist<<<NCHUNK, 256, 0, stream>>>(x, centers, hist);
    km_scan_chunks<<<KC, NCHUNK, 0, stream>>>(hist, clusterStart);
    km_scan_clusters<<<1, 64, 0, stream>>>(clusterStart);
    km_scatter<<<NCHUNK, 256, 0, stream>>>(x, centers, hist, clusterStart, sorted_x);
    km_fold_update<<<KC, 64, 0, stream>>>(sorted_x, clusterStart, centers);
  }
  km_final<<<1024, 256, 0, stream>>>(x, centers, out);
}

// Round 23
// 1885.445 us; speedup vs baseline: 1.4708x; 1.4708x over previous
//
#include <hip/hip_runtime.h>
#include <stdint.h>

#define NPTS (1u << 21)   // 4*512*1024
#define KC 256
#define KM_ITERS 10
#define CHUNK 4096
#define NCHUNK (NPTS / CHUNK)   // 512

// -------- threefry2x32 (JAX PRNG) with explicit key, both output words ------
__device__ __forceinline__ uint32_t rotl32(uint32_t v, uint32_t s) {
  return (v << s) | (v >> (32u - s));
}

__device__ void threefry2x32_key(uint32_t k0, uint32_t k1,
                                 uint32_t c0, uint32_t c1,
                                 uint32_t* o0, uint32_t* o1) {
  uint32_t ks[3] = {k0, k1, k0 ^ k1 ^ 0x1BD11BDAu};
  uint32_t x0 = c0 + ks[0];
  uint32_t x1 = c1 + ks[1];
  const uint32_t rotA[4] = {13u, 15u, 26u, 6u};
  const uint32_t rotB[4] = {17u, 29u, 16u, 24u};
  #pragma unroll
  for (int i = 0; i < 5; ++i) {
    const uint32_t* rot = ((i & 1) == 0) ? rotA : rotB;
    #pragma unroll
    for (int r = 0; r < 4; ++r) {
      x0 += x1;
      x1 = rotl32(x1, rot[r]);
      x1 ^= x0;
    }
    x0 += ks[(i + 1) % 3];
    x1 += ks[(i + 2) % 3] + (uint32_t)(i + 1);
  }
  *o0 = x0;
  *o1 = x1;
}

// init: centers0 = x[randint(key(42),(256,),0,N)]  [R14/R16-validated: exact]
__global__ void km_init(const float* __restrict__ x, float* __restrict__ centers) {
  int j = threadIdx.x;  // 256 threads, 1 block
  uint32_t s0, s1;
  threefry2x32_key(0u, 42u, 0u, 1u, &s0, &s1);      // k2 = split(key(42))[1]
  uint32_t b0, b1;
  threefry2x32_key(s0, s1, 0u, (uint32_t)j, &b0, &b1);
  uint32_t idx = (b0 ^ b1) & (NPTS - 1u);
  centers[j] = x[idx];
}

// sort centers ascending (bitonic, value+orig index); rep[j] = min orig index
// among slots with equal value (exact-duplicate tie groups).
__global__ __launch_bounds__(256) void km_sort_centers(
    const float* __restrict__ centers, float* __restrict__ sortedC,
    uint32_t* __restrict__ rep) {
  __shared__ float v[KC];
  __shared__ int idx[KC];
  __shared__ uint32_t r[KC];
  const int t = threadIdx.x;
  v[t] = centers[t];
  idx[t] = t;
  __syncthreads();
  for (int size = 2; size <= KC; size <<= 1) {
    for (int stride = size >> 1; stride > 0; stride >>= 1) {
      int partner = t ^ stride;
      if (partner > t) {
        bool ascending = ((t & size) == 0);
        float va = v[t], vb = v[partner];
        int ia = idx[t], ib = idx[partner];
        bool doswap = ascending ? (va > vb) : (va < vb);
        if (doswap) { v[t] = vb; v[partner] = va; idx[t] = ib; idx[partner] = ia; }
      }
      __syncthreads();
    }
  }
  if (t == 0) {   // run-min of orig indices over equal-value groups (2 passes)
    float cv = v[0];
    uint32_t cur = (uint32_t)idx[0];
    r[0] = cur;
    for (int j = 1; j < KC; ++j) {
      if (v[j] == cv) { uint32_t ij = (uint32_t)idx[j]; cur = (ij < cur) ? ij : cur; }
      else { cv = v[j]; cur = (uint32_t)idx[j]; }
      r[j] = cur;
    }
    float nv = v[KC - 1];
    uint32_t nc = r[KC - 1];
    for (int j = KC - 2; j >= 0; --j) {
      if (v[j] == nv) { nc = (r[j] < nc) ? r[j] : nc; r[j] = nc; }
      else { nv = v[j]; nc = r[j]; }
    }
  }
  __syncthreads();
  sortedC[t] = v[t];
  rep[t] = r[t];
}

// exact-argmin via sorted binary search: upper-bound (count of <= x, capped
// 255), then 2-candidate f32 compare (same |x-c| ops as reference), ties ->
// min rep (first-original-index semantics). Exact dups handled by rep[].
__device__ __forceinline__ uint32_t bs_label(float x, const float* sC,
                                             const uint32_t* rp) {
  int pos = 0;
  #pragma unroll
  for (int d = 128; d >= 1; d >>= 1)
    if (sC[pos + d - 1] <= x) pos += d;
  if (pos == 0) return rp[0];
  float cl = sC[pos - 1], cr = sC[pos & 255];   // pos<=255 always; &255 for safety
  float dl = fabsf(x - cl), dr = fabsf(x - cr);
  if (dl < dr) return rp[pos - 1];
  if (dr < dl) return rp[pos];
  uint32_t a = rp[pos - 1], b = rp[pos];
  return a < b ? a : b;
}

// assign + per-chunk histogram via binary search (R23: replaces 256-sweep).
__global__ __launch_bounds__(256) void km_assign_hist(
    const float* __restrict__ x, const float* __restrict__ sortedC,
    const uint32_t* __restrict__ rep, uint32_t* __restrict__ hist) {
  __shared__ float sC[KC];
  __shared__ uint32_t rp[KC];
  __shared__ uint32_t sH[KC];
  const int t = threadIdx.x, b = blockIdx.x;
  sC[t] = sortedC[t];
  rp[t] = rep[t];
  sH[t] = 0u;
  __syncthreads();

  #pragma unroll
  for (int q = 0; q < 4; ++q) {
    const int i4 = b * (CHUNK / 4) + q * 256 + t;  // float4 index
    float4 xv = reinterpret_cast<const float4*>(x)[i4];
    uint32_t l0 = bs_label(xv.x, sC, rp);
    uint32_t l1 = bs_label(xv.y, sC, rp);
    uint32_t l2 = bs_label(xv.z, sC, rp);
    uint32_t l3 = bs_label(xv.w, sC, rp);
    atomicAdd(&sH[l0], 1u);
    atomicAdd(&sH[l1], 1u);
    atomicAdd(&sH[l2], 1u);
    atomicAdd(&sH[l3], 1u);
  }
  __syncthreads();
  hist[b * KC + t] = sH[t];
}

// parallel per-cluster exclusive scan over chunks (Hillis-Steele, exact ints).
__global__ __launch_bounds__(512) void km_scan_chunks(
    uint32_t* __restrict__ hist, uint32_t* __restrict__ clusterStart) {
  __shared__ uint32_t s[NCHUNK];
  const int k = blockIdx.x, t = threadIdx.x;
  uint32_t v = hist[t * KC + k];
  s[t] = v;
  __syncthreads();
  #pragma unroll
  for (int d = 1; d < NCHUNK; d <<= 1) {
    uint32_t u = (t >= d) ? s[t - d] : 0u;
    __syncthreads();
    s[t] += u;
    __syncthreads();
  }
  hist[t * KC + k] = s[t] - v;            // exclusive within cluster
  if (t == NCHUNK - 1) clusterStart[k] = s[t];  // total (temp)
}

// serial exclusive scan over the 256 cluster totals -> clusterStart[0..256]
__global__ void km_scan_clusters(uint32_t* __restrict__ clusterStart) {
  if (threadIdx.x != 0) return;
  uint32_t acc = 0;
  for (int j = 0; j < KC; ++j) {
    uint32_t t = clusterStart[j];
    clusterStart[j] = acc;
    acc += t;
  }
  clusterStart[KC] = acc;  // == NPTS
}

// stable scatter into sorted_x (= d_out used as scratch); labels via bs.
__global__ __launch_bounds__(256) void km_scatter(
    const float* __restrict__ x, const float* __restrict__ sortedC,
    const uint32_t* __restrict__ rep,
    const uint32_t* __restrict__ hist, const uint32_t* __restrict__ clusterStart,
    float* __restrict__ sorted_x) {
  __shared__ float sC[KC];
  __shared__ uint32_t rp[KC];
  __shared__ uint32_t run[KC];
  __shared__ uint32_t cntw[4][KC];
  __shared__ uint32_t basew[4][KC];
  const int t = threadIdx.x, b = blockIdx.x;
  const int w = t >> 6, lane = t & 63;
  sC[t] = sortedC[t];
  rp[t] = rep[t];
  run[t] = hist[b * KC + t] + clusterStart[t];
  __syncthreads();

  for (int r = 0; r < CHUNK / 256; ++r) {      // 16 rounds of 256 elements
    const int i = b * CHUNK + r * 256 + t;
    const float xv = x[i];
    uint32_t lab = bs_label(xv, sC, rp);
    unsigned long long m = ~0ULL;
    #pragma unroll
    for (int bit = 0; bit < 8; ++bit) {
      unsigned long long vote = __ballot((lab >> bit) & 1u);
      m &= ((lab >> bit) & 1u) ? vote : ~vote;
    }
    uint32_t rank = (uint32_t)__popcll(m & ((1ULL << lane) - 1ULL));
    uint32_t wcnt = (uint32_t)__popcll(m);
    cntw[0][t] = 0u; cntw[1][t] = 0u; cntw[2][t] = 0u; cntw[3][t] = 0u;
    __syncthreads();
    if (rank == 0) cntw[w][lab] = wcnt;
    __syncthreads();
    {
      uint32_t c0 = cntw[0][t], c1 = cntw[1][t], c2 = cntw[2][t], c3 = cntw[3][t];
      uint32_t base = run[t];
      basew[0][t] = base;
      basew[1][t] = base + c0;
      basew[2][t] = base + c0 + c1;
      basew[3][t] = base + c0 + c1 + c2;
      run[t] = base + c0 + c1 + c2 + c3;
    }
    __syncthreads();
    sorted_x[basew[w][lab] + rank] = xv;
  }
}

// ---- fold helpers: explicit register names, no token pasting ---------------
#define LOADG(p0, p1, p2, p3, p4, p5, p6, p7, base) \
  p0 = b4[(base) + 0]; p1 = b4[(base) + 1];         \
  p2 = b4[(base) + 2]; p3 = b4[(base) + 3];         \
  p4 = b4[(base) + 4]; p5 = b4[(base) + 5];         \
  p6 = b4[(base) + 6]; p7 = b4[(base) + 7];

#define FOLD4(q) s += (q).x; s += (q).y; s += (q).z; s += (q).w;

#define FOLDG(p0, p1, p2, p3, p4, p5, p6, p7) \
  FOLD4(p0) FOLD4(p1) FOLD4(p2) FOLD4(p3)     \
  FOLD4(p4) FOLD4(p5) FOLD4(p6) FOLD4(p7)

// per-cluster sequential f32 left-fold in index order (bitwise == CPU
// scatter-add). R20-validated 256-tile LDS double-buffer + pipelined b128
// reads (161 us; R21/22's 1024-tile was 167 us -> chain-bound, reverted).
__global__ __launch_bounds__(64) void km_fold_update(
    const float* __restrict__ sorted_x, const uint32_t* __restrict__ clusterStart,
    float* __restrict__ centers) {
  __shared__ __align__(16) float buf[2][256];
  const int k = blockIdx.x;
  const uint32_t lane = threadIdx.x;
  const uint32_t s0 = clusterStart[k], s1 = clusterStart[k + 1];
  const uint32_t cnt = s1 - s0;
  const float* p = sorted_x + s0;
  const uint32_t ntiles = (cnt + 255u) >> 8;

  if (ntiles > 0) {
    uint32_t i0 = lane * 4u;
    float4 v = make_float4(0.f, 0.f, 0.f, 0.f);
    if (i0 + 3u < cnt) {
      v = *reinterpret_cast<const float4*>(p + i0);
    } else {
      if (i0 + 0u < cnt) v.x = p[i0 + 0u];
      if (i0 + 1u < cnt) v.y = p[i0 + 1u];
      if (i0 + 2u < cnt) v.z = p[i0 + 2u];
    }
    *reinterpret_cast<float4*>(&buf[0][lane * 4u]) = v;
  }
  __syncthreads();

  float s = 0.0f;
  for (uint32_t t = 0; t < ntiles; ++t) {
    const bool have_next = (t + 1u < ntiles);
    float4 vn = make_float4(0.f, 0.f, 0.f, 0.f);
    if (have_next) {
      uint32_t i0 = (t + 1u) * 256u + lane * 4u;
      if (i0 + 3u < cnt) {
        vn = *reinterpret_cast<const float4*>(p + i0);
      } else {
        if (i0 + 0u < cnt) vn.x = p[i0 + 0u];
        if (i0 + 1u < cnt) vn.y = p[i0 + 1u];
        if (i0 + 2u < cnt) vn.z = p[i0 + 2u];
      }
    }
    if (lane == 0) {
      const float* bb = buf[t & 1u];
      uint32_t m = cnt - t * 256u;
      if (m > 256u) m = 256u;
      if (m == 256u) {
        const float4* b4 = reinterpret_cast<const float4*>(bb);
        float4 a0, a1, a2, a3, a4, a5, a6, a7;
        float4 c0, c1, c2, c3, c4, c5, c6, c7;
        LOADG(a0, a1, a2, a3, a4, a5, a6, a7, 0)
        LOADG(c0, c1, c2, c3, c4, c5, c6, c7, 8)
        FOLDG(a0, a1, a2, a3, a4, a5, a6, a7)
        LOADG(a0, a1, a2, a3, a4, a5, a6, a7, 16)
        FOLDG(c0, c1, c2, c3, c4, c5, c6, c7)
        LOADG(c0, c1, c2, c3, c4, c5, c6, c7, 24)
        FOLDG(a0, a1, a2, a3, a4, a5, a6, a7)
        LOADG(a0, a1, a2, a3, a4, a5, a6, a7, 32)
        FOLDG(c0, c1, c2, c3, c4, c5, c6, c7)
        LOADG(c0, c1, c2, c3, c4, c5, c6, c7, 40)
        FOLDG(a0, a1, a2, a3, a4, a5, a6, a7)
        LOADG(a0, a1, a2, a3, a4, a5, a6, a7, 48)
        FOLDG(c0, c1, c2, c3, c4, c5, c6, c7)
        LOADG(c0, c1, c2, c3, c4, c5, c6, c7, 56)
        FOLDG(a0, a1, a2, a3, a4, a5, a6, a7)
        FOLDG(c0, c1, c2, c3, c4, c5, c6, c7)
      } else {
        uint32_t j = 0;
        for (; j + 16u <= m; j += 16u) {
          float v0 = bb[j + 0], v1 = bb[j + 1], v2 = bb[j + 2], v3 = bb[j + 3];
          float v4 = bb[j + 4], v5 = bb[j + 5], v6 = bb[j + 6], v7 = bb[j + 7];
          float v8 = bb[j + 8], v9 = bb[j + 9], va = bb[j + 10], vb = bb[j + 11];
          float vc = bb[j + 12], vd = bb[j + 13], ve = bb[j + 14], vf = bb[j + 15];
          s += v0; s += v1; s += v2; s += v3;
          s += v4; s += v5; s += v6; s += v7;
          s += v8; s += v9; s += va; s += vb;
          s += vc; s += vd; s += ve; s += vf;
        }
        for (; j < m; ++j) s += bb[j];
      }
    }
    if (have_next) {
      *reinterpret_cast<float4*>(&buf[(t + 1u) & 1u][lane * 4u]) = vn;
    }
    __syncthreads();
  }
  if (lane == 0 && cnt > 0) centers[k] = s / (float)cnt;  // else keep old
}

// final assign + gather via binary search: out = centers[labels]
__global__ __launch_bounds__(256) void km_final(
    const float* __restrict__ x, const float* __restrict__ centers,
    const float* __restrict__ sortedC, const uint32_t* __restrict__ rep,
    float* __restrict__ out) {
  __shared__ float sC[KC];
  __shared__ uint32_t rp[KC];
  __shared__ float sCtr[KC];
  const int t = threadIdx.x;
  sC[t] = sortedC[t];
  rp[t] = rep[t];
  sCtr[t] = centers[t];
  __syncthreads();

  const int nv = (int)(NPTS / 4u);
  for (int i = blockIdx.x * blockDim.x + t; i < nv; i += gridDim.x * blockDim.x) {
    float4 xv = reinterpret_cast<const float4*>(x)[i];
    float4 o;
    o.x = sCtr[bs_label(xv.x, sC, rp)];
    o.y = sCtr[bs_label(xv.y, sC, rp)];
    o.z = sCtr[bs_label(xv.z, sC, rp)];
    o.w = sCtr[bs_label(xv.w, sC, rp)];
    reinterpret_cast<float4*>(out)[i] = o;
  }
}

extern "C" void kernel_launch(void* const* d_in, const int* in_sizes, int n_in,
                              void* d_out, int out_size, void* d_ws, size_t ws_size,
                              hipStream_t stream) {
  const float* x = (const float*)d_in[0];
  float* out = (float*)d_out;

  // ws layout (~520 KB):
  //   [0,1K)       centers f32[256]
  //   [1K,2.1K)    clusterStart u32[257]
  //   [2.5K,3.5K)  sortedC f32[256]
  //   [3.5K,4.5K)  rep u32[256]
  //   [8K,520K)    hist u32[512][256]
  // sorted_x (8 MB) lives in d_out — dead after fold, overwritten by km_final.
  uint8_t* ws = (uint8_t*)d_ws;
  float* centers = (float*)(ws + 0);
  uint32_t* clusterStart = (uint32_t*)(ws + 1024);
  float* sortedC = (float*)(ws + 2560);
  uint32_t* rep = (uint32_t*)(ws + 3584);
  uint32_t* hist = (uint32_t*)(ws + 8192);
  float* sorted_x = (float*)d_out;

  km_init<<<1, KC, 0, stream>>>(x, centers);
  for (int it = 0; it < KM_ITERS; ++it) {
    km_sort_centers<<<1, KC, 0, stream>>>(centers, sortedC, rep);
    km_assign_hist<<<NCHUNK, 256, 0, stream>>>(x, sortedC, rep, hist);
    km_scan_chunks<<<KC, NCHUNK, 0, stream>>>(hist, clusterStart);
    km_scan_clusters<<<1, 64, 0, stream>>>(clusterStart);
    km_scatter<<<NCHUNK, 256, 0, stream>>>(x, sortedC, rep, hist, clusterStart,
                                           sorted_x);
    km_fold_update<<<KC, 64, 0, stream>>>(sorted_x, clusterStart, centers);
  }
  km_sort_centers<<<1, KC, 0, stream>>>(centers, sortedC, rep);
  km_final<<<1024, 256, 0, stream>>>(x, centers, sortedC, rep, out);
}